// Round 15
// baseline (363.133 us; speedup 1.0000x reference)
//
#include <hip/hip_runtime.h>
#include <stdint.h>

// R21: gemms REVERTED to R19's 128² m97-structure (R20's 256² was neutral:
// 192/128-block grids idle 25-50% of CUs at 1 block/CU; coarse phase-split
// is m196-null). attn: two contained changes, no VGPR growth:
//  1. KVBLK=128: two K/V tiles per barrier window (sequential tile_step,
//     transient st regs). Barriers/block 33->17, staging batched 8 gloads.
//     LDS 32->64KB caps 2 blocks/CU = measured residency (no occ loss).
//  2. T5 setprio(1) around QK and PV MFMA clusters (m191: +4-7% attn in
//     this multi-block/CU regime).
// Everything else = R19 (326.3us: attn 96.6, conflicts 0).

typedef unsigned short u16;
typedef short bf16x8 __attribute__((ext_vector_type(8)));
typedef float f32x4 __attribute__((ext_vector_type(4)));

#define D_MODEL 2048
#define QKV_DIM 3072
#define NUM_HEADS 32
#define HEAD_DIM 64
#define SEQ 2048
#define MTOT 4096

static __device__ __forceinline__ u16 f2bf(float f){
  uint32_t u = __builtin_bit_cast(uint32_t, f);
  u += 0x7FFFu + ((u >> 16) & 1u);
  return (u16)(u >> 16);
}

static __device__ __forceinline__ float exp2_fast(float x){
  float r;
  asm("v_exp_f32 %0, %1" : "=v"(r) : "v"(x));
  return r;
}

static __device__ __forceinline__ uint32_t cvt_pk_bf16(float lo, float hi){
  uint32_t r;
  asm("v_cvt_pk_bf16_f32 %0, %1, %2" : "=v"(r) : "v"(lo), "v"(hi));
  return r;
}

static __device__ __forceinline__ void gload16(const u16* g, u16* l){
  __builtin_amdgcn_global_load_lds(
      (__attribute__((address_space(1))) uint32_t*)(uintptr_t)g,
      (__attribute__((address_space(3))) uint32_t*)l,
      16, 0, 0);
}

static __device__ __forceinline__ void cvt8(const float* __restrict__ src,
                                            u16* __restrict__ dst,
                                            int i, float scl){
  float4 a = *(const float4*)(src + i);
  float4 b = *(const float4*)(src + i + 4);
  union { u16 h[8]; uint4 v; } t;
  t.h[0]=f2bf(a.x*scl); t.h[1]=f2bf(a.y*scl); t.h[2]=f2bf(a.z*scl); t.h[3]=f2bf(a.w*scl);
  t.h[4]=f2bf(b.x*scl); t.h[5]=f2bf(b.y*scl); t.h[6]=f2bf(b.z*scl); t.h[7]=f2bf(b.w*scl);
  *(uint4*)(dst + i) = t.v;
}

__global__ __launch_bounds__(256)
void cvt_bf16(const float* __restrict__ in, u16* __restrict__ out, int n,
              float scl){
  const int i = (blockIdx.x * 256 + threadIdx.x) * 8;
  if (i >= n) return;
  cvt8(in, out, i, scl);
}

// Fused conversion of all inputs: block-range dispatch (uniform branch).
__global__ __launch_bounds__(256)
void cvt_all(const float* __restrict__ x,  const float* __restrict__ Wq,
             const float* __restrict__ Wk, const float* __restrict__ Wv,
             const float* __restrict__ Wo,
             u16* __restrict__ xb, u16* __restrict__ Wb,
             u16* __restrict__ Wob, float qscl){
  const int bid = blockIdx.x;
  const float* src; u16* dst; int off; float scl = 1.0f;
  if (bid < 4096){        src = x;  dst = xb;                              off = bid;        }
  else if (bid < 6144){   src = Wq; dst = Wb;                              off = bid - 4096; scl = qscl; }
  else if (bid < 6656){   src = Wk; dst = Wb + (size_t)D_MODEL*D_MODEL;    off = bid - 6144; }
  else if (bid < 7168){   src = Wv; dst = Wb + (size_t)2560*D_MODEL;       off = bid - 6656; }
  else {                  src = Wo; dst = Wob;                             off = bid - 7168; }
  const int i = (off * 256 + threadIdx.x) * 8;
  cvt8(src, dst, i, scl);
}

// C[M,N] = A[M,K] @ B[N,K]^T. m97 structure (BK=32), 1-D grid with
// bijective XCD swizzle.
template <bool F32OUT>
__global__ __launch_bounds__(256)
void gemm_bt(const u16* __restrict__ A, const u16* __restrict__ B,
             void* __restrict__ Cv, int M, int N, int K, int nbx){
  constexpr int BK = 32;
  __shared__ __attribute__((aligned(16))) u16 As[128*BK];
  __shared__ __attribute__((aligned(16))) u16 Bs[128*BK];
  const int tid  = threadIdx.x;
  const int wave = tid >> 6, lane = tid & 63;
  const int quad = lane >> 4, l16 = lane & 15;
  const int wrow = wave >> 1, wcol = wave & 1;
  const int nwg = gridDim.x;
  const int qq = nwg >> 3, rr = nwg & 7;
  const int xcd = blockIdx.x & 7, lin = blockIdx.x >> 3;
  const int swz = (xcd < rr ? xcd*(qq+1) : rr*(qq+1) + (xcd-rr)*qq) + lin;
  const int m0 = (swz / nbx) * 128, n0 = (swz % nbx) * 128;
  const int srow = lane >> 2, scol = (lane & 3) * 8;

  const f32x4 zero = {0.f, 0.f, 0.f, 0.f};
  f32x4 acc[4][4];
#pragma unroll
  for (int i = 0; i < 4; i++)
#pragma unroll
    for (int j = 0; j < 4; j++) acc[i][j] = zero;

  for (int k0 = 0; k0 < K; k0 += BK){
#pragma unroll
    for (int t = 0; t < 2; t++){
      const int chunk = wave + t*4;
      gload16(A + (size_t)(m0 + chunk*16 + srow)*K + k0 + scol, As + chunk*16*BK);
      gload16(B + (size_t)(n0 + chunk*16 + srow)*K + k0 + scol, Bs + chunk*16*BK);
    }
    __syncthreads();
    bf16x8 af[4], bfr[4];
#pragma unroll
    for (int mi = 0; mi < 4; mi++)
      af[mi] = *(const bf16x8*)(As + (wrow*64 + mi*16 + l16)*BK + quad*8);
#pragma unroll
    for (int ni = 0; ni < 4; ni++)
      bfr[ni] = *(const bf16x8*)(Bs + (wcol*64 + ni*16 + l16)*BK + quad*8);
#pragma unroll
    for (int mi = 0; mi < 4; mi++)
#pragma unroll
      for (int ni = 0; ni < 4; ni++)
        acc[mi][ni] = __builtin_amdgcn_mfma_f32_16x16x32_bf16(af[mi], bfr[ni], acc[mi][ni], 0, 0, 0);
    __syncthreads();
  }
#pragma unroll
  for (int mi = 0; mi < 4; mi++)
#pragma unroll
    for (int ni = 0; ni < 4; ni++){
      const int col = n0 + wcol*64 + ni*16 + l16;
#pragma unroll
      for (int r = 0; r < 4; r++){
        const int row = m0 + wrow*64 + mi*16 + quad*4 + r;
        if constexpr (F32OUT)
          ((float*)Cv)[(size_t)row*N + col] = acc[mi][ni][r];
        else
          ((u16*)Cv)[(size_t)row*N + col] = f2bf(acc[mi][ni][r]);
      }
    }
}

// kvtrans: per-(b,hk,j) 8KB K/V tiles in the exact swizzled LDS image.
__global__ __launch_bounds__(256)
void kvtrans(const u16* __restrict__ QKV, u16* __restrict__ Ksw,
             u16* __restrict__ Vsw){
  __shared__ u16 Ls[64*72];
  const int tid = threadIdx.x;
  const int st = blockIdx.x, hk = blockIdx.y, b = blockIdx.z;
  const size_t rb = (size_t)b * SEQ;
  const size_t tbase = ((size_t)(b*8 + hk)*32 + st) * 4096;

#pragma unroll
  for (int t = 0; t < 2; t++){
    const int task = t*256 + tid;
    const int r = task >> 3, c = task & 7;
    uint4 kv = *(const uint4*)(QKV + (rb + st*64 + r)*QKV_DIM + 2048 + hk*HEAD_DIM + c*8);
    *(uint4*)(Ksw + tbase + r*64 + (size_t)((c ^ (r & 7)) * 8)) = kv;
  }
#pragma unroll
  for (int t = 0; t < 2; t++){
    const int task = t*256 + tid;
    const int r = task >> 3, c = task & 7;
    *(uint4*)(Ls + r*72 + c*8) =
        *(const uint4*)(QKV + (rb + st*64 + r)*QKV_DIM + 2560 + hk*HEAD_DIM + c*8);
  }
  __syncthreads();
#pragma unroll
  for (int t = 0; t < 2; t++){
    const int task = t*256 + tid;
    const int d = task >> 3, sc = task & 7;
    union { u16 h[8]; uint4 v; } tmp;
#pragma unroll
    for (int e = 0; e < 8; e++){
      const int key = ((2*(sc>>2) + (e>>2))<<4) + ((sc&3)<<2) + (e&3);
      tmp.h[e] = Ls[key*72 + d];
    }
    *(uint4*)(Vsw + tbase + d*64 + (size_t)((sc ^ (d & 7)) * 8)) = tmp.v;
  }
}

// one tile's QK + online-softmax (log2, defer-max) + in-register P + PV,
// with T5 setprio around the MFMA clusters.
static __device__ __forceinline__ void tile_step(
    const u16* __restrict__ Ksb, const u16* __restrict__ Vtb,
    const bf16x8* qf, f32x4* oacc, float& m_i, float& l_i,
    int quad, int l16, int sw, bool diag, int qrow){
  const f32x4 zero = {0.f, 0.f, 0.f, 0.f};
  f32x4 st[4];
  __builtin_amdgcn_s_setprio(1);
#pragma unroll
  for (int ni = 0; ni < 4; ni++){
    f32x4 s = zero;
#pragma unroll
    for (int ss = 0; ss < 2; ss++){
      bf16x8 kf = *(const bf16x8*)(Ksb + ((ni*16 + l16) << 6) +
                                   (((ss*4 + quad) ^ sw) << 3));
      s = __builtin_amdgcn_mfma_f32_16x16x32_bf16(kf, qf[ss], s, 0, 0, 0);
    }
    st[ni] = s;
  }
  __builtin_amdgcn_s_setprio(0);
  if (diag){
#pragma unroll
    for (int ni = 0; ni < 4; ni++)
#pragma unroll
      for (int r = 0; r < 4; r++)
        if (ni*16 + quad*4 + r > qrow) st[ni][r] = -INFINITY;
  }
  float mx = fmaxf(fmaxf(fmaxf(st[0][0], st[0][1]), fmaxf(st[0][2], st[0][3])),
                   fmaxf(fmaxf(st[1][0], st[1][1]), fmaxf(st[1][2], st[1][3])));
  mx = fmaxf(mx, fmaxf(fmaxf(fmaxf(st[2][0], st[2][1]), fmaxf(st[2][2], st[2][3])),
                       fmaxf(fmaxf(st[3][0], st[3][1]), fmaxf(st[3][2], st[3][3]))));
  mx = fmaxf(mx, __shfl_xor(mx, 16));
  mx = fmaxf(mx, __shfl_xor(mx, 32));

  if (__all(mx <= m_i + 10.f)){
    float ps = 0.f;
#pragma unroll
    for (int ni = 0; ni < 4; ni++)
#pragma unroll
      for (int r = 0; r < 4; r++){
        const float p = exp2_fast(st[ni][r] - m_i);
        st[ni][r] = p;
        ps += p;
      }
    ps += __shfl_xor(ps, 16);
    ps += __shfl_xor(ps, 32);
    l_i += ps;
  } else {
    const float mn = fmaxf(m_i, mx);
    const float alpha = exp2_fast(m_i - mn);
    float ps = 0.f;
#pragma unroll
    for (int ni = 0; ni < 4; ni++)
#pragma unroll
      for (int r = 0; r < 4; r++){
        const float p = exp2_fast(st[ni][r] - mn);
        st[ni][r] = p;
        ps += p;
      }
    ps += __shfl_xor(ps, 16);
    ps += __shfl_xor(ps, 32);
    l_i = l_i*alpha + ps;
    m_i = mn;
    float ar[4];
#pragma unroll
    for (int r = 0; r < 4; r++) ar[r] = __shfl(alpha, quad*4 + r);
#pragma unroll
    for (int ci = 0; ci < 4; ci++)
#pragma unroll
      for (int r = 0; r < 4; r++) oacc[ci][r] *= ar[r];
  }

  bf16x8 pfr[2];
#pragma unroll
  for (int ss = 0; ss < 2; ss++){
    union { uint32_t w[4]; bf16x8 v; } pk;
    pk.w[0] = cvt_pk_bf16(st[2*ss][0],   st[2*ss][1]);
    pk.w[1] = cvt_pk_bf16(st[2*ss][2],   st[2*ss][3]);
    pk.w[2] = cvt_pk_bf16(st[2*ss+1][0], st[2*ss+1][1]);
    pk.w[3] = cvt_pk_bf16(st[2*ss+1][2], st[2*ss+1][3]);
    pfr[ss] = pk.v;
  }
  __builtin_amdgcn_s_setprio(1);
#pragma unroll
  for (int ss = 0; ss < 2; ss++)
#pragma unroll
    for (int ci = 0; ci < 4; ci++){
      bf16x8 vf = *(const bf16x8*)(Vtb + ((ci*16 + l16) << 6) +
                                   (((ss*4 + quad) ^ sw) << 3));
      oacc[ci] = __builtin_amdgcn_mfma_f32_16x16x32_bf16(pfr[ss], vf, oacc[ci], 0, 0, 0);
    }
  __builtin_amdgcn_s_setprio(0);
}

// attn: KVBLK=128 (two tiles per barrier window), swapped QK^T, in-register
// P, log2 softmax + defer-max, complement-balanced qt, dbuf gload_lds.
__global__ __launch_bounds__(256)
void attn(const u16* __restrict__ Q, const u16* __restrict__ Ksw,
          const u16* __restrict__ Vsw, u16* __restrict__ O, int qs){
  __shared__ __attribute__((aligned(16))) u16 Ks[2][2*4096];
  __shared__ __attribute__((aligned(16))) u16 Vt[2][2*4096];
  const int tid = threadIdx.x;
  const int wave = tid >> 6, lane = tid & 63, quad = lane >> 4, l16 = lane & 15;
  const int g_ = (blockIdx.x + blockIdx.y) & 31;
  const int qt = blockIdx.z ? (31 - g_) : g_;
  const int h = blockIdx.y, b = blockIdx.z;
  const int hk = h >> 2;
  const size_t rb = (size_t)b * SEQ;
  const size_t hb = ((size_t)(b*8 + hk)) * 32;

  const int qrow = wave*16 + l16;
  const int sw = l16 & 7;

  bf16x8 qf[2];
  {
    const u16* qp = Q + (rb + qt*64 + wave*16 + l16)*qs + h*HEAD_DIM;
    qf[0] = *(const bf16x8*)(qp + quad*8);
    qf[1] = *(const bf16x8*)(qp + 32 + quad*8);
  }
  const f32x4 zero = {0.f, 0.f, 0.f, 0.f};
  f32x4 oacc[4];
#pragma unroll
  for (int i = 0; i < 4; i++) oacc[i] = zero;
  float m_i = -INFINITY;
  float l_i = 0.f;

  // stage tile j into (buf, slot)
#define STAGE_T(j_, buf_, slot_)                                            \
  {                                                                         \
    const u16* kt_ = Ksw + (hb + (j_)) * 4096;                              \
    const u16* vt_ = Vsw + (hb + (j_)) * 4096;                              \
    _Pragma("unroll")                                                       \
    for (int t = 0; t < 2; t++){                                            \
      const int ch = wave*2 + t;                                            \
      gload16(kt_ + ch*512 + lane*8, &Ks[buf_][(slot_)*4096 + ch*512]);     \
      gload16(vt_ + ch*512 + lane*8, &Vt[buf_][(slot_)*4096 + ch*512]);     \
    }                                                                       \
  }

  const int NP = (qt >> 1) + 1;   // pairs: j0 = 0,2,...,2*(NP-1)

  // prologue: stage pair 0 into buffer 0
  STAGE_T(0, 0, 0);
  if (qt >= 1) STAGE_T(1, 0, 1);
  int cur = 0;

  for (int p = 0; p < NP; ++p){
    __syncthreads();   // pair p staged & visible; prior reads of cur^1 done
    if (p + 1 < NP){
      const int jn = 2*p + 2;
      STAGE_T(jn, cur^1, 0);
      if (jn + 1 <= qt) STAGE_T(jn + 1, cur^1, 1);
    }
    const int j0 = 2*p;
    tile_step(&Ks[cur][0], &Vt[cur][0], qf, oacc, m_i, l_i,
              quad, l16, sw, j0 == qt, qrow);
    if (j0 + 1 <= qt)
      tile_step(&Ks[cur][4096], &Vt[cur][4096], qf, oacc, m_i, l_i,
                quad, l16, sw, j0 + 1 == qt, qrow);
    cur ^= 1;
  }
#undef STAGE_T

  float lf[4];
#pragma unroll
  for (int r = 0; r < 4; r++) lf[r] = __shfl(l_i, quad*4 + r);
#pragma unroll
  for (int ci = 0; ci < 4; ci++)
#pragma unroll
    for (int r = 0; r < 4; r++){
      const size_t row = rb + qt*64 + wave*16 + quad*4 + r;
      O[row*D_MODEL + h*HEAD_DIM + ci*16 + l16] = f2bf(oacc[ci][r] / lf[r]);
    }
}

extern "C" void kernel_launch(void* const* d_in, const int* in_sizes, int n_in,
                              void* d_out, int out_size, void* d_ws, size_t ws_size,
                              hipStream_t stream){
  const float* x  = (const float*)d_in[0];
  const float* Wq = (const float*)d_in[1];
  const float* Wk = (const float*)d_in[2];
  const float* Wv = (const float*)d_in[3];
  const float* Wo = (const float*)d_in[4];
  float* out = (float*)d_out;

  u16* xb   = (u16*)d_ws;                    // x / later attn-out  [4096,2048]
  u16* Wb   = xb + (size_t)MTOT*D_MODEL;     // fused weights [3072,2048]
  u16* Wob  = Wb + (size_t)QKV_DIM*D_MODEL;  // Wo bf16 [2048,2048] (if ws fits)
  u16* QKVb = (u16*)d_out;                   // QKV scratch [4096,3072] bf16
  u16* Kswz = Wb;                            // swizzled K tiles (Wq region, dead after gemm1)
  u16* Vswz = Wb + (size_t)2*1024*1024;      // swizzled V tiles

  const int nwq = D_MODEL*D_MODEL;
  const float QSCL = 0.125f * 1.44269504f;   // softmax scale * log2(e)

  const size_t ws_need = ((size_t)MTOT*D_MODEL + (size_t)QKV_DIM*D_MODEL +
                          (size_t)D_MODEL*D_MODEL) * sizeof(u16);
  const bool wob_fits = (ws_size >= ws_need);

  if (wob_fits){
    cvt_all<<<9216, 256, 0, stream>>>(x, Wq, Wk, Wv, Wo, xb, Wb, Wob, QSCL);
  } else {
    cvt_all<<<7168, 256, 0, stream>>>(x, Wq, Wk, Wv, Wo, xb, Wb, Wob, QSCL);
  }
  gemm_bt<false><<<(QKV_DIM/128)*(MTOT/128), 256, 0, stream>>>(
      xb, Wb, QKVb, MTOT, QKV_DIM, D_MODEL, QKV_DIM/128);
  kvtrans<<<dim3(SEQ/64, 8, 2), 256, 0, stream>>>(QKVb, Kswz, Vswz);
  attn<<<dim3(SEQ/64, NUM_HEADS, 2), 256, 0, stream>>>(
      QKVb, Kswz, Vswz, xb, QKV_DIM);
  const u16* Bw2;
  if (wob_fits){
    Bw2 = Wob;
  } else {
    cvt_bf16<<<nwq/2048, 256, 0, stream>>>(Wo, Wb, nwq, 1.0f);
    Bw2 = Wb;
  }
  gemm_bt<true><<<(D_MODEL/128)*(MTOT/128), 256, 0, stream>>>(
      xb, Bw2, (void*)out, MTOT, D_MODEL, D_MODEL, D_MODEL/128);
}

// Round 16
// 321.578 us; speedup vs baseline: 1.1292x; 1.1292x over previous
//
#include <hip/hip_runtime.h>
#include <stdint.h>

// R22: attn reverted to R19 dataflow, then ONE axis changed that none of the
// four failed structure gambles (R9/R13/R18/R21) touched: waves/block.
// 512-thread blocks, QBLK=128: 8 waves each own 16 q-rows with per-thread
// state BYTE-IDENTICAL to R19 (qf[2], oacc[4], m, l); all 8 waves share the
// SAME 32KB double-buffered K/V staging. Staging + barriers per q-row halve,
// resident waves/CU doubles at equal block residency (4 blocks/CU thread
// limit = 32 waves/CU). Causal: wave w needs tile j iff j <= 2t + (w>=4)
// (wave-uniform skip); diag mask uses qrow_eff=(w&3)*16+l16. Total MFMA
// work unchanged; K/V FETCH ~halves. gemms/cvt_all/kvtrans = R19 verbatim.

typedef unsigned short u16;
typedef short bf16x8 __attribute__((ext_vector_type(8)));
typedef float f32x4 __attribute__((ext_vector_type(4)));

#define D_MODEL 2048
#define QKV_DIM 3072
#define NUM_HEADS 32
#define HEAD_DIM 64
#define SEQ 2048
#define MTOT 4096

static __device__ __forceinline__ u16 f2bf(float f){
  uint32_t u = __builtin_bit_cast(uint32_t, f);
  u += 0x7FFFu + ((u >> 16) & 1u);
  return (u16)(u >> 16);
}

static __device__ __forceinline__ float exp2_fast(float x){
  float r;
  asm("v_exp_f32 %0, %1" : "=v"(r) : "v"(x));
  return r;
}

static __device__ __forceinline__ uint32_t cvt_pk_bf16(float lo, float hi){
  uint32_t r;
  asm("v_cvt_pk_bf16_f32 %0, %1, %2" : "=v"(r) : "v"(lo), "v"(hi));
  return r;
}

static __device__ __forceinline__ void gload16(const u16* g, u16* l){
  __builtin_amdgcn_global_load_lds(
      (__attribute__((address_space(1))) uint32_t*)(uintptr_t)g,
      (__attribute__((address_space(3))) uint32_t*)l,
      16, 0, 0);
}

static __device__ __forceinline__ void cvt8(const float* __restrict__ src,
                                            u16* __restrict__ dst,
                                            int i, float scl){
  float4 a = *(const float4*)(src + i);
  float4 b = *(const float4*)(src + i + 4);
  union { u16 h[8]; uint4 v; } t;
  t.h[0]=f2bf(a.x*scl); t.h[1]=f2bf(a.y*scl); t.h[2]=f2bf(a.z*scl); t.h[3]=f2bf(a.w*scl);
  t.h[4]=f2bf(b.x*scl); t.h[5]=f2bf(b.y*scl); t.h[6]=f2bf(b.z*scl); t.h[7]=f2bf(b.w*scl);
  *(uint4*)(dst + i) = t.v;
}

__global__ __launch_bounds__(256)
void cvt_bf16(const float* __restrict__ in, u16* __restrict__ out, int n,
              float scl){
  const int i = (blockIdx.x * 256 + threadIdx.x) * 8;
  if (i >= n) return;
  cvt8(in, out, i, scl);
}

// Fused conversion of all inputs: block-range dispatch (uniform branch).
__global__ __launch_bounds__(256)
void cvt_all(const float* __restrict__ x,  const float* __restrict__ Wq,
             const float* __restrict__ Wk, const float* __restrict__ Wv,
             const float* __restrict__ Wo,
             u16* __restrict__ xb, u16* __restrict__ Wb,
             u16* __restrict__ Wob, float qscl){
  const int bid = blockIdx.x;
  const float* src; u16* dst; int off; float scl = 1.0f;
  if (bid < 4096){        src = x;  dst = xb;                              off = bid;        }
  else if (bid < 6144){   src = Wq; dst = Wb;                              off = bid - 4096; scl = qscl; }
  else if (bid < 6656){   src = Wk; dst = Wb + (size_t)D_MODEL*D_MODEL;    off = bid - 6144; }
  else if (bid < 7168){   src = Wv; dst = Wb + (size_t)2560*D_MODEL;       off = bid - 6656; }
  else {                  src = Wo; dst = Wob;                             off = bid - 7168; }
  const int i = (off * 256 + threadIdx.x) * 8;
  cvt8(src, dst, i, scl);
}

// C[M,N] = A[M,K] @ B[N,K]^T. m97 structure (BK=32), bijective XCD swizzle.
template <bool F32OUT>
__global__ __launch_bounds__(256)
void gemm_bt(const u16* __restrict__ A, const u16* __restrict__ B,
             void* __restrict__ Cv, int M, int N, int K, int nbx){
  constexpr int BK = 32;
  __shared__ __attribute__((aligned(16))) u16 As[128*BK];
  __shared__ __attribute__((aligned(16))) u16 Bs[128*BK];
  const int tid  = threadIdx.x;
  const int wave = tid >> 6, lane = tid & 63;
  const int quad = lane >> 4, l16 = lane & 15;
  const int wrow = wave >> 1, wcol = wave & 1;
  const int nwg = gridDim.x;
  const int qq = nwg >> 3, rr = nwg & 7;
  const int xcd = blockIdx.x & 7, lin = blockIdx.x >> 3;
  const int swz = (xcd < rr ? xcd*(qq+1) : rr*(qq+1) + (xcd-rr)*qq) + lin;
  const int m0 = (swz / nbx) * 128, n0 = (swz % nbx) * 128;
  const int srow = lane >> 2, scol = (lane & 3) * 8;

  const f32x4 zero = {0.f, 0.f, 0.f, 0.f};
  f32x4 acc[4][4];
#pragma unroll
  for (int i = 0; i < 4; i++)
#pragma unroll
    for (int j = 0; j < 4; j++) acc[i][j] = zero;

  for (int k0 = 0; k0 < K; k0 += BK){
#pragma unroll
    for (int t = 0; t < 2; t++){
      const int chunk = wave + t*4;
      gload16(A + (size_t)(m0 + chunk*16 + srow)*K + k0 + scol, As + chunk*16*BK);
      gload16(B + (size_t)(n0 + chunk*16 + srow)*K + k0 + scol, Bs + chunk*16*BK);
    }
    __syncthreads();
    bf16x8 af[4], bfr[4];
#pragma unroll
    for (int mi = 0; mi < 4; mi++)
      af[mi] = *(const bf16x8*)(As + (wrow*64 + mi*16 + l16)*BK + quad*8);
#pragma unroll
    for (int ni = 0; ni < 4; ni++)
      bfr[ni] = *(const bf16x8*)(Bs + (wcol*64 + ni*16 + l16)*BK + quad*8);
#pragma unroll
    for (int mi = 0; mi < 4; mi++)
#pragma unroll
      for (int ni = 0; ni < 4; ni++)
        acc[mi][ni] = __builtin_amdgcn_mfma_f32_16x16x32_bf16(af[mi], bfr[ni], acc[mi][ni], 0, 0, 0);
    __syncthreads();
  }
#pragma unroll
  for (int mi = 0; mi < 4; mi++)
#pragma unroll
    for (int ni = 0; ni < 4; ni++){
      const int col = n0 + wcol*64 + ni*16 + l16;
#pragma unroll
      for (int r = 0; r < 4; r++){
        const int row = m0 + wrow*64 + mi*16 + quad*4 + r;
        if constexpr (F32OUT)
          ((float*)Cv)[(size_t)row*N + col] = acc[mi][ni][r];
        else
          ((u16*)Cv)[(size_t)row*N + col] = f2bf(acc[mi][ni][r]);
      }
    }
}

// kvtrans: per-(b,hk,j) 8KB K/V tiles in the exact swizzled LDS image.
__global__ __launch_bounds__(256)
void kvtrans(const u16* __restrict__ QKV, u16* __restrict__ Ksw,
             u16* __restrict__ Vsw){
  __shared__ u16 Ls[64*72];
  const int tid = threadIdx.x;
  const int st = blockIdx.x, hk = blockIdx.y, b = blockIdx.z;
  const size_t rb = (size_t)b * SEQ;
  const size_t tbase = ((size_t)(b*8 + hk)*32 + st) * 4096;

#pragma unroll
  for (int t = 0; t < 2; t++){
    const int task = t*256 + tid;
    const int r = task >> 3, c = task & 7;
    uint4 kv = *(const uint4*)(QKV + (rb + st*64 + r)*QKV_DIM + 2048 + hk*HEAD_DIM + c*8);
    *(uint4*)(Ksw + tbase + r*64 + (size_t)((c ^ (r & 7)) * 8)) = kv;
  }
#pragma unroll
  for (int t = 0; t < 2; t++){
    const int task = t*256 + tid;
    const int r = task >> 3, c = task & 7;
    *(uint4*)(Ls + r*72 + c*8) =
        *(const uint4*)(QKV + (rb + st*64 + r)*QKV_DIM + 2560 + hk*HEAD_DIM + c*8);
  }
  __syncthreads();
#pragma unroll
  for (int t = 0; t < 2; t++){
    const int task = t*256 + tid;
    const int d = task >> 3, sc = task & 7;
    union { u16 h[8]; uint4 v; } tmp;
#pragma unroll
    for (int e = 0; e < 8; e++){
      const int key = ((2*(sc>>2) + (e>>2))<<4) + ((sc&3)<<2) + (e&3);
      tmp.h[e] = Ls[key*72 + d];
    }
    *(uint4*)(Vsw + tbase + d*64 + (size_t)((sc ^ (d & 7)) * 8)) = tmp.v;
  }
}

// attn: 512 threads / 8 waves, QBLK=128. Per-thread dataflow = R19 verbatim
// (swapped QK^T, in-register P, log2 softmax + defer-max, dbuf gload_lds
// staging, XOR-swizzled reads). Waves share one 32KB staged K/V pipeline.
__global__ __launch_bounds__(512)
void attn(const u16* __restrict__ Q, const u16* __restrict__ Ksw,
          const u16* __restrict__ Vsw, u16* __restrict__ O, int qs){
  __shared__ __attribute__((aligned(16))) u16 Ks[2][4096];
  __shared__ __attribute__((aligned(16))) u16 Vt[2][4096];
  const int tid = threadIdx.x;
  const int wid = tid >> 6, lane = tid & 63, quad = lane >> 4, l16 = lane & 15;
  // complement-balanced q-block pair across batch dim (16 pairs)
  const int g_ = (blockIdx.x + blockIdx.y) & 15;
  const int tb = blockIdx.z ? (15 - g_) : g_;    // q-rows [tb*128, tb*128+128)
  const int h = blockIdx.y, b = blockIdx.z;
  const int hk = h >> 2;
  const size_t rb = (size_t)b * SEQ;
  const size_t hb = ((size_t)(b*8 + hk)) * 32;

  const int qtB   = 2*tb + 1;                 // last 64-key tile this block needs
  const int jmaxw = 2*tb + (wid >> 2);        // last tile THIS wave needs
  const int qrow  = (wid & 3)*16 + l16;       // row within this wave's diag tile
  const int sw = l16 & 7;

  bf16x8 qf[2];
  {
    const u16* qp = Q + (rb + tb*128 + wid*16 + l16)*qs + h*HEAD_DIM;
    qf[0] = *(const bf16x8*)(qp + quad*8);
    qf[1] = *(const bf16x8*)(qp + 32 + quad*8);
  }
  const f32x4 zero = {0.f, 0.f, 0.f, 0.f};
  f32x4 oacc[4];
#pragma unroll
  for (int i = 0; i < 4; i++) oacc[i] = zero;
  float m_i = -INFINITY;
  float l_i = 0.f;

  // stage tile j into buffer buf_: 512 threads x 1 gload16 each for K and V
#define STAGE_T(j_, buf_)                                                   \
  {                                                                         \
    gload16(Ksw + (hb + (j_)) * 4096 + wid*512 + lane*8, &Ks[buf_][wid*512]); \
    gload16(Vsw + (hb + (j_)) * 4096 + wid*512 + lane*8, &Vt[buf_][wid*512]); \
  }

  STAGE_T(0, 0);
  int cur = 0;

  for (int j = 0; j <= qtB; ++j){
    __syncthreads();   // buf[cur] staged & visible; prior reads of cur^1 done
    if (j < qtB) STAGE_T(j + 1, cur^1);

    if (j <= jmaxw){   // wave-uniform causal skip
      const u16* Ksb = Ks[cur];
      const u16* Vtb = Vt[cur];

      f32x4 st[4];
#pragma unroll
      for (int ni = 0; ni < 4; ni++){
        f32x4 s = zero;
#pragma unroll
        for (int ss = 0; ss < 2; ss++){
          bf16x8 kf = *(const bf16x8*)(Ksb + ((ni*16 + l16) << 6) +
                                       (((ss*4 + quad) ^ sw) << 3));
          s = __builtin_amdgcn_mfma_f32_16x16x32_bf16(kf, qf[ss], s, 0, 0, 0);
        }
        st[ni] = s;
      }
      if (j == jmaxw){
#pragma unroll
        for (int ni = 0; ni < 4; ni++)
#pragma unroll
          for (int r = 0; r < 4; r++)
            if (ni*16 + quad*4 + r > qrow) st[ni][r] = -INFINITY;
      }

      float mx = fmaxf(fmaxf(fmaxf(st[0][0], st[0][1]), fmaxf(st[0][2], st[0][3])),
                       fmaxf(fmaxf(st[1][0], st[1][1]), fmaxf(st[1][2], st[1][3])));
      mx = fmaxf(mx, fmaxf(fmaxf(fmaxf(st[2][0], st[2][1]), fmaxf(st[2][2], st[2][3])),
                           fmaxf(fmaxf(st[3][0], st[3][1]), fmaxf(st[3][2], st[3][3]))));
      mx = fmaxf(mx, __shfl_xor(mx, 16));
      mx = fmaxf(mx, __shfl_xor(mx, 32));

      if (__all(mx <= m_i + 10.f)){
        float ps = 0.f;
#pragma unroll
        for (int ni = 0; ni < 4; ni++)
#pragma unroll
          for (int r = 0; r < 4; r++){
            const float p = exp2_fast(st[ni][r] - m_i);
            st[ni][r] = p;
            ps += p;
          }
        ps += __shfl_xor(ps, 16);
        ps += __shfl_xor(ps, 32);
        l_i += ps;
      } else {
        const float mn = fmaxf(m_i, mx);
        const float alpha = exp2_fast(m_i - mn);
        float ps = 0.f;
#pragma unroll
        for (int ni = 0; ni < 4; ni++)
#pragma unroll
          for (int r = 0; r < 4; r++){
            const float p = exp2_fast(st[ni][r] - mn);
            st[ni][r] = p;
            ps += p;
          }
        ps += __shfl_xor(ps, 16);
        ps += __shfl_xor(ps, 32);
        l_i = l_i*alpha + ps;
        m_i = mn;
        float ar[4];
#pragma unroll
        for (int r = 0; r < 4; r++) ar[r] = __shfl(alpha, quad*4 + r);
#pragma unroll
        for (int ci = 0; ci < 4; ci++)
#pragma unroll
          for (int r = 0; r < 4; r++) oacc[ci][r] *= ar[r];
      }

      bf16x8 pfr[2];
#pragma unroll
      for (int ss = 0; ss < 2; ss++){
        union { uint32_t w[4]; bf16x8 v; } pk;
        pk.w[0] = cvt_pk_bf16(st[2*ss][0],   st[2*ss][1]);
        pk.w[1] = cvt_pk_bf16(st[2*ss][2],   st[2*ss][3]);
        pk.w[2] = cvt_pk_bf16(st[2*ss+1][0], st[2*ss+1][1]);
        pk.w[3] = cvt_pk_bf16(st[2*ss+1][2], st[2*ss+1][3]);
        pfr[ss] = pk.v;
      }

#pragma unroll
      for (int ss = 0; ss < 2; ss++)
#pragma unroll
        for (int ci = 0; ci < 4; ci++){
          bf16x8 vf = *(const bf16x8*)(Vtb + ((ci*16 + l16) << 6) +
                                       (((ss*4 + quad) ^ sw) << 3));
          oacc[ci] = __builtin_amdgcn_mfma_f32_16x16x32_bf16(pfr[ss], vf, oacc[ci], 0, 0, 0);
        }
    }
    cur ^= 1;
  }
#undef STAGE_T

  float lf[4];
#pragma unroll
  for (int r = 0; r < 4; r++) lf[r] = __shfl(l_i, quad*4 + r);
#pragma unroll
  for (int ci = 0; ci < 4; ci++)
#pragma unroll
    for (int r = 0; r < 4; r++){
      const size_t row = rb + tb*128 + wid*16 + quad*4 + r;
      O[row*D_MODEL + h*HEAD_DIM + ci*16 + l16] = f2bf(oacc[ci][r] / lf[r]);
    }
}

extern "C" void kernel_launch(void* const* d_in, const int* in_sizes, int n_in,
                              void* d_out, int out_size, void* d_ws, size_t ws_size,
                              hipStream_t stream){
  const float* x  = (const float*)d_in[0];
  const float* Wq = (const float*)d_in[1];
  const float* Wk = (const float*)d_in[2];
  const float* Wv = (const float*)d_in[3];
  const float* Wo = (const float*)d_in[4];
  float* out = (float*)d_out;

  u16* xb   = (u16*)d_ws;                    // x / later attn-out  [4096,2048]
  u16* Wb   = xb + (size_t)MTOT*D_MODEL;     // fused weights [3072,2048]
  u16* Wob  = Wb + (size_t)QKV_DIM*D_MODEL;  // Wo bf16 [2048,2048] (if ws fits)
  u16* QKVb = (u16*)d_out;                   // QKV scratch [4096,3072] bf16
  u16* Kswz = Wb;                            // swizzled K tiles (Wq region, dead after gemm1)
  u16* Vswz = Wb + (size_t)2*1024*1024;      // swizzled V tiles

  const int nwq = D_MODEL*D_MODEL;
  const float QSCL = 0.125f * 1.44269504f;   // softmax scale * log2(e)

  const size_t ws_need = ((size_t)MTOT*D_MODEL + (size_t)QKV_DIM*D_MODEL +
                          (size_t)D_MODEL*D_MODEL) * sizeof(u16);
  const bool wob_fits = (ws_size >= ws_need);

  if (wob_fits){
    cvt_all<<<9216, 256, 0, stream>>>(x, Wq, Wk, Wv, Wo, xb, Wb, Wob, QSCL);
  } else {
    cvt_all<<<7168, 256, 0, stream>>>(x, Wq, Wk, Wv, Wo, xb, Wb, Wob, QSCL);
  }
  gemm_bt<false><<<(QKV_DIM/128)*(MTOT/128), 256, 0, stream>>>(
      xb, Wb, QKVb, MTOT, QKV_DIM, D_MODEL, QKV_DIM/128);
  kvtrans<<<dim3(SEQ/64, 8, 2), 256, 0, stream>>>(QKVb, Kswz, Vswz);
  attn<<<dim3(16, NUM_HEADS, 2), 512, 0, stream>>>(
      QKVb, Kswz, Vswz, xb, QKV_DIM);
  const u16* Bw2;
  if (wob_fits){
    Bw2 = Wob;
  } else {
    cvt_bf16<<<nwq/2048, 256, 0, stream>>>(Wo, Wb, nwq, 1.0f);
    Bw2 = Wb;
  }
  gemm_bt<true><<<(D_MODEL/128)*(MTOT/128), 256, 0, stream>>>(
      xb, Bw2, (void*)out, MTOT, D_MODEL, D_MODEL, D_MODEL/128);
}

// Round 17
// 314.397 us; speedup vs baseline: 1.1550x; 1.0228x over previous
//
#include <hip/hip_runtime.h>
#include <stdint.h>

// R23: base = R22 (321.6us, best: attn 90.0 at 512-thread/8-wave QBLK=128).
// ONE change, same axis that won in R22 (amortize staging+barriers across
// more compute without growing per-thread state): KVBLK=128 — each barrier
// window stages TWO 64-key tiles (4 gload16/thread) and processes them
// sequentially with transient st regs. Windows per block halve (2tb+2 ->
// tb+1, always exact since tile count is even). LDS 32->64KB caps residency
// at 2 blocks/CU = 16 waves/CU > measured ~8.4 (unlike R21's 256-thread cap
// which bit below residency). Per-thread state byte-identical to R22.
// gemms/cvt_all/kvtrans = R22 verbatim.

typedef unsigned short u16;
typedef short bf16x8 __attribute__((ext_vector_type(8)));
typedef float f32x4 __attribute__((ext_vector_type(4)));

#define D_MODEL 2048
#define QKV_DIM 3072
#define NUM_HEADS 32
#define HEAD_DIM 64
#define SEQ 2048
#define MTOT 4096

static __device__ __forceinline__ u16 f2bf(float f){
  uint32_t u = __builtin_bit_cast(uint32_t, f);
  u += 0x7FFFu + ((u >> 16) & 1u);
  return (u16)(u >> 16);
}

static __device__ __forceinline__ float exp2_fast(float x){
  float r;
  asm("v_exp_f32 %0, %1" : "=v"(r) : "v"(x));
  return r;
}

static __device__ __forceinline__ uint32_t cvt_pk_bf16(float lo, float hi){
  uint32_t r;
  asm("v_cvt_pk_bf16_f32 %0, %1, %2" : "=v"(r) : "v"(lo), "v"(hi));
  return r;
}

static __device__ __forceinline__ void gload16(const u16* g, u16* l){
  __builtin_amdgcn_global_load_lds(
      (__attribute__((address_space(1))) uint32_t*)(uintptr_t)g,
      (__attribute__((address_space(3))) uint32_t*)l,
      16, 0, 0);
}

static __device__ __forceinline__ void cvt8(const float* __restrict__ src,
                                            u16* __restrict__ dst,
                                            int i, float scl){
  float4 a = *(const float4*)(src + i);
  float4 b = *(const float4*)(src + i + 4);
  union { u16 h[8]; uint4 v; } t;
  t.h[0]=f2bf(a.x*scl); t.h[1]=f2bf(a.y*scl); t.h[2]=f2bf(a.z*scl); t.h[3]=f2bf(a.w*scl);
  t.h[4]=f2bf(b.x*scl); t.h[5]=f2bf(b.y*scl); t.h[6]=f2bf(b.z*scl); t.h[7]=f2bf(b.w*scl);
  *(uint4*)(dst + i) = t.v;
}

__global__ __launch_bounds__(256)
void cvt_bf16(const float* __restrict__ in, u16* __restrict__ out, int n,
              float scl){
  const int i = (blockIdx.x * 256 + threadIdx.x) * 8;
  if (i >= n) return;
  cvt8(in, out, i, scl);
}

// Fused conversion of all inputs: block-range dispatch (uniform branch).
__global__ __launch_bounds__(256)
void cvt_all(const float* __restrict__ x,  const float* __restrict__ Wq,
             const float* __restrict__ Wk, const float* __restrict__ Wv,
             const float* __restrict__ Wo,
             u16* __restrict__ xb, u16* __restrict__ Wb,
             u16* __restrict__ Wob, float qscl){
  const int bid = blockIdx.x;
  const float* src; u16* dst; int off; float scl = 1.0f;
  if (bid < 4096){        src = x;  dst = xb;                              off = bid;        }
  else if (bid < 6144){   src = Wq; dst = Wb;                              off = bid - 4096; scl = qscl; }
  else if (bid < 6656){   src = Wk; dst = Wb + (size_t)D_MODEL*D_MODEL;    off = bid - 6144; }
  else if (bid < 7168){   src = Wv; dst = Wb + (size_t)2560*D_MODEL;       off = bid - 6656; }
  else {                  src = Wo; dst = Wob;                             off = bid - 7168; }
  const int i = (off * 256 + threadIdx.x) * 8;
  cvt8(src, dst, i, scl);
}

// C[M,N] = A[M,K] @ B[N,K]^T. m97 structure (BK=32), bijective XCD swizzle.
template <bool F32OUT>
__global__ __launch_bounds__(256)
void gemm_bt(const u16* __restrict__ A, const u16* __restrict__ B,
             void* __restrict__ Cv, int M, int N, int K, int nbx){
  constexpr int BK = 32;
  __shared__ __attribute__((aligned(16))) u16 As[128*BK];
  __shared__ __attribute__((aligned(16))) u16 Bs[128*BK];
  const int tid  = threadIdx.x;
  const int wave = tid >> 6, lane = tid & 63;
  const int quad = lane >> 4, l16 = lane & 15;
  const int wrow = wave >> 1, wcol = wave & 1;
  const int nwg = gridDim.x;
  const int qq = nwg >> 3, rr = nwg & 7;
  const int xcd = blockIdx.x & 7, lin = blockIdx.x >> 3;
  const int swz = (xcd < rr ? xcd*(qq+1) : rr*(qq+1) + (xcd-rr)*qq) + lin;
  const int m0 = (swz / nbx) * 128, n0 = (swz % nbx) * 128;
  const int srow = lane >> 2, scol = (lane & 3) * 8;

  const f32x4 zero = {0.f, 0.f, 0.f, 0.f};
  f32x4 acc[4][4];
#pragma unroll
  for (int i = 0; i < 4; i++)
#pragma unroll
    for (int j = 0; j < 4; j++) acc[i][j] = zero;

  for (int k0 = 0; k0 < K; k0 += BK){
#pragma unroll
    for (int t = 0; t < 2; t++){
      const int chunk = wave + t*4;
      gload16(A + (size_t)(m0 + chunk*16 + srow)*K + k0 + scol, As + chunk*16*BK);
      gload16(B + (size_t)(n0 + chunk*16 + srow)*K + k0 + scol, Bs + chunk*16*BK);
    }
    __syncthreads();
    bf16x8 af[4], bfr[4];
#pragma unroll
    for (int mi = 0; mi < 4; mi++)
      af[mi] = *(const bf16x8*)(As + (wrow*64 + mi*16 + l16)*BK + quad*8);
#pragma unroll
    for (int ni = 0; ni < 4; ni++)
      bfr[ni] = *(const bf16x8*)(Bs + (wcol*64 + ni*16 + l16)*BK + quad*8);
#pragma unroll
    for (int mi = 0; mi < 4; mi++)
#pragma unroll
      for (int ni = 0; ni < 4; ni++)
        acc[mi][ni] = __builtin_amdgcn_mfma_f32_16x16x32_bf16(af[mi], bfr[ni], acc[mi][ni], 0, 0, 0);
    __syncthreads();
  }
#pragma unroll
  for (int mi = 0; mi < 4; mi++)
#pragma unroll
    for (int ni = 0; ni < 4; ni++){
      const int col = n0 + wcol*64 + ni*16 + l16;
#pragma unroll
      for (int r = 0; r < 4; r++){
        const int row = m0 + wrow*64 + mi*16 + quad*4 + r;
        if constexpr (F32OUT)
          ((float*)Cv)[(size_t)row*N + col] = acc[mi][ni][r];
        else
          ((u16*)Cv)[(size_t)row*N + col] = f2bf(acc[mi][ni][r]);
      }
    }
}

// kvtrans: per-(b,hk,j) 8KB K/V tiles in the exact swizzled LDS image.
__global__ __launch_bounds__(256)
void kvtrans(const u16* __restrict__ QKV, u16* __restrict__ Ksw,
             u16* __restrict__ Vsw){
  __shared__ u16 Ls[64*72];
  const int tid = threadIdx.x;
  const int st = blockIdx.x, hk = blockIdx.y, b = blockIdx.z;
  const size_t rb = (size_t)b * SEQ;
  const size_t tbase = ((size_t)(b*8 + hk)*32 + st) * 4096;

#pragma unroll
  for (int t = 0; t < 2; t++){
    const int task = t*256 + tid;
    const int r = task >> 3, c = task & 7;
    uint4 kv = *(const uint4*)(QKV + (rb + st*64 + r)*QKV_DIM + 2048 + hk*HEAD_DIM + c*8);
    *(uint4*)(Ksw + tbase + r*64 + (size_t)((c ^ (r & 7)) * 8)) = kv;
  }
#pragma unroll
  for (int t = 0; t < 2; t++){
    const int task = t*256 + tid;
    const int r = task >> 3, c = task & 7;
    *(uint4*)(Ls + r*72 + c*8) =
        *(const uint4*)(QKV + (rb + st*64 + r)*QKV_DIM + 2560 + hk*HEAD_DIM + c*8);
  }
  __syncthreads();
#pragma unroll
  for (int t = 0; t < 2; t++){
    const int task = t*256 + tid;
    const int d = task >> 3, sc = task & 7;
    union { u16 h[8]; uint4 v; } tmp;
#pragma unroll
    for (int e = 0; e < 8; e++){
      const int key = ((2*(sc>>2) + (e>>2))<<4) + ((sc&3)<<2) + (e&3);
      tmp.h[e] = Ls[key*72 + d];
    }
    *(uint4*)(Vsw + tbase + d*64 + (size_t)((sc ^ (d & 7)) * 8)) = tmp.v;
  }
}

// attn: 512 threads / 8 waves, QBLK=128, KVBLK=128 (two tiles per barrier
// window, sequential slots, transient st). Per-thread dataflow = R22.
__global__ __launch_bounds__(512)
void attn(const u16* __restrict__ Q, const u16* __restrict__ Ksw,
          const u16* __restrict__ Vsw, u16* __restrict__ O, int qs){
  __shared__ __attribute__((aligned(16))) u16 Ks[2][2*4096];
  __shared__ __attribute__((aligned(16))) u16 Vt[2][2*4096];
  const int tid = threadIdx.x;
  const int wid = tid >> 6, lane = tid & 63, quad = lane >> 4, l16 = lane & 15;
  const int g_ = (blockIdx.x + blockIdx.y) & 15;
  const int tb = blockIdx.z ? (15 - g_) : g_;    // q-rows [tb*128, tb*128+128)
  const int h = blockIdx.y, b = blockIdx.z;
  const int hk = h >> 2;
  const size_t rb = (size_t)b * SEQ;
  const size_t hb = ((size_t)(b*8 + hk)) * 32;

  const int jmaxw = 2*tb + (wid >> 2);        // last 64-key tile THIS wave needs
  const int qrow  = (wid & 3)*16 + l16;       // row within this wave's diag tile
  const int sw = l16 & 7;

  bf16x8 qf[2];
  {
    const u16* qp = Q + (rb + tb*128 + wid*16 + l16)*qs + h*HEAD_DIM;
    qf[0] = *(const bf16x8*)(qp + quad*8);
    qf[1] = *(const bf16x8*)(qp + 32 + quad*8);
  }
  const f32x4 zero = {0.f, 0.f, 0.f, 0.f};
  f32x4 oacc[4];
#pragma unroll
  for (int i = 0; i < 4; i++) oacc[i] = zero;
  float m_i = -INFINITY;
  float l_i = 0.f;

  // stage tile PAIR p (tiles 2p, 2p+1) into buffer buf_: 4 gload16/thread
#define STAGE_P(p_, buf_)                                                     \
  {                                                                           \
    const size_t t0 = (hb + 2*(size_t)(p_)) * 4096;                           \
    gload16(Ksw + t0        + wid*512 + lane*8, &Ks[buf_][wid*512]);          \
    gload16(Ksw + t0 + 4096 + wid*512 + lane*8, &Ks[buf_][4096 + wid*512]);   \
    gload16(Vsw + t0        + wid*512 + lane*8, &Vt[buf_][wid*512]);          \
    gload16(Vsw + t0 + 4096 + wid*512 + lane*8, &Vt[buf_][4096 + wid*512]);   \
  }

  const int NP = tb + 1;   // pairs; tile count per block = 2tb+2 (even)
  STAGE_P(0, 0);
  int cur = 0;

  for (int p = 0; p < NP; ++p){
    __syncthreads();   // pair p staged & visible; prior reads of cur^1 done
    if (p + 1 < NP) STAGE_P(p + 1, cur^1);

#pragma unroll
    for (int s = 0; s < 2; ++s){
      const int j = 2*p + s;
      if (j <= jmaxw){   // wave-uniform causal skip
        const u16* Ksb = &Ks[cur][s*4096];
        const u16* Vtb = &Vt[cur][s*4096];

        f32x4 st[4];
#pragma unroll
        for (int ni = 0; ni < 4; ni++){
          f32x4 sacc = zero;
#pragma unroll
          for (int ss = 0; ss < 2; ss++){
            bf16x8 kf = *(const bf16x8*)(Ksb + ((ni*16 + l16) << 6) +
                                         (((ss*4 + quad) ^ sw) << 3));
            sacc = __builtin_amdgcn_mfma_f32_16x16x32_bf16(kf, qf[ss], sacc, 0, 0, 0);
          }
          st[ni] = sacc;
        }
        if (j == jmaxw){
#pragma unroll
          for (int ni = 0; ni < 4; ni++)
#pragma unroll
            for (int r = 0; r < 4; r++)
              if (ni*16 + quad*4 + r > qrow) st[ni][r] = -INFINITY;
        }

        float mx = fmaxf(fmaxf(fmaxf(st[0][0], st[0][1]), fmaxf(st[0][2], st[0][3])),
                         fmaxf(fmaxf(st[1][0], st[1][1]), fmaxf(st[1][2], st[1][3])));
        mx = fmaxf(mx, fmaxf(fmaxf(fmaxf(st[2][0], st[2][1]), fmaxf(st[2][2], st[2][3])),
                             fmaxf(fmaxf(st[3][0], st[3][1]), fmaxf(st[3][2], st[3][3]))));
        mx = fmaxf(mx, __shfl_xor(mx, 16));
        mx = fmaxf(mx, __shfl_xor(mx, 32));

        if (__all(mx <= m_i + 10.f)){
          float ps = 0.f;
#pragma unroll
          for (int ni = 0; ni < 4; ni++)
#pragma unroll
            for (int r = 0; r < 4; r++){
              const float pv = exp2_fast(st[ni][r] - m_i);
              st[ni][r] = pv;
              ps += pv;
            }
          ps += __shfl_xor(ps, 16);
          ps += __shfl_xor(ps, 32);
          l_i += ps;
        } else {
          const float mn = fmaxf(m_i, mx);
          const float alpha = exp2_fast(m_i - mn);
          float ps = 0.f;
#pragma unroll
          for (int ni = 0; ni < 4; ni++)
#pragma unroll
            for (int r = 0; r < 4; r++){
              const float pv = exp2_fast(st[ni][r] - mn);
              st[ni][r] = pv;
              ps += pv;
            }
          ps += __shfl_xor(ps, 16);
          ps += __shfl_xor(ps, 32);
          l_i = l_i*alpha + ps;
          m_i = mn;
          float ar[4];
#pragma unroll
          for (int r = 0; r < 4; r++) ar[r] = __shfl(alpha, quad*4 + r);
#pragma unroll
          for (int ci = 0; ci < 4; ci++)
#pragma unroll
            for (int r = 0; r < 4; r++) oacc[ci][r] *= ar[r];
        }

        bf16x8 pfr[2];
#pragma unroll
        for (int ss = 0; ss < 2; ss++){
          union { uint32_t w[4]; bf16x8 v; } pk;
          pk.w[0] = cvt_pk_bf16(st[2*ss][0],   st[2*ss][1]);
          pk.w[1] = cvt_pk_bf16(st[2*ss][2],   st[2*ss][3]);
          pk.w[2] = cvt_pk_bf16(st[2*ss+1][0], st[2*ss+1][1]);
          pk.w[3] = cvt_pk_bf16(st[2*ss+1][2], st[2*ss+1][3]);
          pfr[ss] = pk.v;
        }

#pragma unroll
        for (int ss = 0; ss < 2; ss++)
#pragma unroll
          for (int ci = 0; ci < 4; ci++){
            bf16x8 vf = *(const bf16x8*)(Vtb + ((ci*16 + l16) << 6) +
                                         (((ss*4 + quad) ^ sw) << 3));
            oacc[ci] = __builtin_amdgcn_mfma_f32_16x16x32_bf16(pfr[ss], vf, oacc[ci], 0, 0, 0);
          }
      }
    }
    cur ^= 1;
  }
#undef STAGE_P

  float lf[4];
#pragma unroll
  for (int r = 0; r < 4; r++) lf[r] = __shfl(l_i, quad*4 + r);
#pragma unroll
  for (int ci = 0; ci < 4; ci++)
#pragma unroll
    for (int r = 0; r < 4; r++){
      const size_t row = rb + tb*128 + wid*16 + quad*4 + r;
      O[row*D_MODEL + h*HEAD_DIM + ci*16 + l16] = f2bf(oacc[ci][r] / lf[r]);
    }
}

extern "C" void kernel_launch(void* const* d_in, const int* in_sizes, int n_in,
                              void* d_out, int out_size, void* d_ws, size_t ws_size,
                              hipStream_t stream){
  const float* x  = (const float*)d_in[0];
  const float* Wq = (const float*)d_in[1];
  const float* Wk = (const float*)d_in[2];
  const float* Wv = (const float*)d_in[3];
  const float* Wo = (const float*)d_in[4];
  float* out = (float*)d_out;

  u16* xb   = (u16*)d_ws;                    // x / later attn-out  [4096,2048]
  u16* Wb   = xb + (size_t)MTOT*D_MODEL;     // fused weights [3072,2048]
  u16* Wob  = Wb + (size_t)QKV_DIM*D_MODEL;  // Wo bf16 [2048,2048] (if ws fits)
  u16* QKVb = (u16*)d_out;                   // QKV scratch [4096,3072] bf16
  u16* Kswz = Wb;                            // swizzled K tiles (Wq region, dead after gemm1)
  u16* Vswz = Wb + (size_t)2*1024*1024;      // swizzled V tiles

  const int nwq = D_MODEL*D_MODEL;
  const float QSCL = 0.125f * 1.44269504f;   // softmax scale * log2(e)

  const size_t ws_need = ((size_t)MTOT*D_MODEL + (size_t)QKV_DIM*D_MODEL +
                          (size_t)D_MODEL*D_MODEL) * sizeof(u16);
  const bool wob_fits = (ws_size >= ws_need);

  if (wob_fits){
    cvt_all<<<9216, 256, 0, stream>>>(x, Wq, Wk, Wv, Wo, xb, Wb, Wob, QSCL);
  } else {
    cvt_all<<<7168, 256, 0, stream>>>(x, Wq, Wk, Wv, Wo, xb, Wb, Wob, QSCL);
  }
  gemm_bt<false><<<(QKV_DIM/128)*(MTOT/128), 256, 0, stream>>>(
      xb, Wb, QKVb, MTOT, QKV_DIM, D_MODEL, QKV_DIM/128);
  kvtrans<<<dim3(SEQ/64, 8, 2), 256, 0, stream>>>(QKVb, Kswz, Vswz);
  attn<<<dim3(16, NUM_HEADS, 2), 512, 0, stream>>>(
      QKVb, Kswz, Vswz, xb, QKV_DIM);
  const u16* Bw2;
  if (wob_fits){
    Bw2 = Wob;
  } else {
    cvt_bf16<<<nwq/2048, 256, 0, stream>>>(Wo, Wb, nwq, 1.0f);
    Bw2 = Wb;
  }
  gemm_bt<true><<<(D_MODEL/128)*(MTOT/128), 256, 0, stream>>>(
      xb, Bw2, (void*)out, MTOT, D_MODEL, D_MODEL, D_MODEL/128);
}

// Round 18
// 303.010 us; speedup vs baseline: 1.1984x; 1.0376x over previous
//
#include <hip/hip_runtime.h>
#include <stdint.h>

// R24: base = R23 verbatim (314.4us best) except attn's BLOCK ORDERING.
// Diagnosis: 1024 blocks / 2 resident per CU, and the (x+y)&15 hash gives
// each CU initial residents {g, 15-g} twice -> CU makespan = its longest
// blocks; tb=15 stragglers (32 windows) set global makespan while center-g
// CUs idle after ~18 -> ~50-60% utilization (matches stuck 25% occupancy).
// Fix: explicit LPT dispatch. 1-D grid, longest-first decode:
//   tb = 15 - (bid>>6), h = bid&31, b = (bid>>5)&1   (bijective, 64/tb)
// First 512 dispatched = long half (fully resident at t=0); short half
// queues and backfills CUs dynamically. Zero dataflow change.

typedef unsigned short u16;
typedef short bf16x8 __attribute__((ext_vector_type(8)));
typedef float f32x4 __attribute__((ext_vector_type(4)));

#define D_MODEL 2048
#define QKV_DIM 3072
#define NUM_HEADS 32
#define HEAD_DIM 64
#define SEQ 2048
#define MTOT 4096

static __device__ __forceinline__ u16 f2bf(float f){
  uint32_t u = __builtin_bit_cast(uint32_t, f);
  u += 0x7FFFu + ((u >> 16) & 1u);
  return (u16)(u >> 16);
}

static __device__ __forceinline__ float exp2_fast(float x){
  float r;
  asm("v_exp_f32 %0, %1" : "=v"(r) : "v"(x));
  return r;
}

static __device__ __forceinline__ uint32_t cvt_pk_bf16(float lo, float hi){
  uint32_t r;
  asm("v_cvt_pk_bf16_f32 %0, %1, %2" : "=v"(r) : "v"(lo), "v"(hi));
  return r;
}

static __device__ __forceinline__ void gload16(const u16* g, u16* l){
  __builtin_amdgcn_global_load_lds(
      (__attribute__((address_space(1))) uint32_t*)(uintptr_t)g,
      (__attribute__((address_space(3))) uint32_t*)l,
      16, 0, 0);
}

static __device__ __forceinline__ void cvt8(const float* __restrict__ src,
                                            u16* __restrict__ dst,
                                            int i, float scl){
  float4 a = *(const float4*)(src + i);
  float4 b = *(const float4*)(src + i + 4);
  union { u16 h[8]; uint4 v; } t;
  t.h[0]=f2bf(a.x*scl); t.h[1]=f2bf(a.y*scl); t.h[2]=f2bf(a.z*scl); t.h[3]=f2bf(a.w*scl);
  t.h[4]=f2bf(b.x*scl); t.h[5]=f2bf(b.y*scl); t.h[6]=f2bf(b.z*scl); t.h[7]=f2bf(b.w*scl);
  *(uint4*)(dst + i) = t.v;
}

__global__ __launch_bounds__(256)
void cvt_bf16(const float* __restrict__ in, u16* __restrict__ out, int n,
              float scl){
  const int i = (blockIdx.x * 256 + threadIdx.x) * 8;
  if (i >= n) return;
  cvt8(in, out, i, scl);
}

// Fused conversion of all inputs: block-range dispatch (uniform branch).
__global__ __launch_bounds__(256)
void cvt_all(const float* __restrict__ x,  const float* __restrict__ Wq,
             const float* __restrict__ Wk, const float* __restrict__ Wv,
             const float* __restrict__ Wo,
             u16* __restrict__ xb, u16* __restrict__ Wb,
             u16* __restrict__ Wob, float qscl){
  const int bid = blockIdx.x;
  const float* src; u16* dst; int off; float scl = 1.0f;
  if (bid < 4096){        src = x;  dst = xb;                              off = bid;        }
  else if (bid < 6144){   src = Wq; dst = Wb;                              off = bid - 4096; scl = qscl; }
  else if (bid < 6656){   src = Wk; dst = Wb + (size_t)D_MODEL*D_MODEL;    off = bid - 6144; }
  else if (bid < 7168){   src = Wv; dst = Wb + (size_t)2560*D_MODEL;       off = bid - 6656; }
  else {                  src = Wo; dst = Wob;                             off = bid - 7168; }
  const int i = (off * 256 + threadIdx.x) * 8;
  cvt8(src, dst, i, scl);
}

// C[M,N] = A[M,K] @ B[N,K]^T. m97 structure (BK=32), bijective XCD swizzle.
template <bool F32OUT>
__global__ __launch_bounds__(256)
void gemm_bt(const u16* __restrict__ A, const u16* __restrict__ B,
             void* __restrict__ Cv, int M, int N, int K, int nbx){
  constexpr int BK = 32;
  __shared__ __attribute__((aligned(16))) u16 As[128*BK];
  __shared__ __attribute__((aligned(16))) u16 Bs[128*BK];
  const int tid  = threadIdx.x;
  const int wave = tid >> 6, lane = tid & 63;
  const int quad = lane >> 4, l16 = lane & 15;
  const int wrow = wave >> 1, wcol = wave & 1;
  const int nwg = gridDim.x;
  const int qq = nwg >> 3, rr = nwg & 7;
  const int xcd = blockIdx.x & 7, lin = blockIdx.x >> 3;
  const int swz = (xcd < rr ? xcd*(qq+1) : rr*(qq+1) + (xcd-rr)*qq) + lin;
  const int m0 = (swz / nbx) * 128, n0 = (swz % nbx) * 128;
  const int srow = lane >> 2, scol = (lane & 3) * 8;

  const f32x4 zero = {0.f, 0.f, 0.f, 0.f};
  f32x4 acc[4][4];
#pragma unroll
  for (int i = 0; i < 4; i++)
#pragma unroll
    for (int j = 0; j < 4; j++) acc[i][j] = zero;

  for (int k0 = 0; k0 < K; k0 += BK){
#pragma unroll
    for (int t = 0; t < 2; t++){
      const int chunk = wave + t*4;
      gload16(A + (size_t)(m0 + chunk*16 + srow)*K + k0 + scol, As + chunk*16*BK);
      gload16(B + (size_t)(n0 + chunk*16 + srow)*K + k0 + scol, Bs + chunk*16*BK);
    }
    __syncthreads();
    bf16x8 af[4], bfr[4];
#pragma unroll
    for (int mi = 0; mi < 4; mi++)
      af[mi] = *(const bf16x8*)(As + (wrow*64 + mi*16 + l16)*BK + quad*8);
#pragma unroll
    for (int ni = 0; ni < 4; ni++)
      bfr[ni] = *(const bf16x8*)(Bs + (wcol*64 + ni*16 + l16)*BK + quad*8);
#pragma unroll
    for (int mi = 0; mi < 4; mi++)
#pragma unroll
      for (int ni = 0; ni < 4; ni++)
        acc[mi][ni] = __builtin_amdgcn_mfma_f32_16x16x32_bf16(af[mi], bfr[ni], acc[mi][ni], 0, 0, 0);
    __syncthreads();
  }
#pragma unroll
  for (int mi = 0; mi < 4; mi++)
#pragma unroll
    for (int ni = 0; ni < 4; ni++){
      const int col = n0 + wcol*64 + ni*16 + l16;
#pragma unroll
      for (int r = 0; r < 4; r++){
        const int row = m0 + wrow*64 + mi*16 + quad*4 + r;
        if constexpr (F32OUT)
          ((float*)Cv)[(size_t)row*N + col] = acc[mi][ni][r];
        else
          ((u16*)Cv)[(size_t)row*N + col] = f2bf(acc[mi][ni][r]);
      }
    }
}

// kvtrans: per-(b,hk,j) 8KB K/V tiles in the exact swizzled LDS image.
__global__ __launch_bounds__(256)
void kvtrans(const u16* __restrict__ QKV, u16* __restrict__ Ksw,
             u16* __restrict__ Vsw){
  __shared__ u16 Ls[64*72];
  const int tid = threadIdx.x;
  const int st = blockIdx.x, hk = blockIdx.y, b = blockIdx.z;
  const size_t rb = (size_t)b * SEQ;
  const size_t tbase = ((size_t)(b*8 + hk)*32 + st) * 4096;

#pragma unroll
  for (int t = 0; t < 2; t++){
    const int task = t*256 + tid;
    const int r = task >> 3, c = task & 7;
    uint4 kv = *(const uint4*)(QKV + (rb + st*64 + r)*QKV_DIM + 2048 + hk*HEAD_DIM + c*8);
    *(uint4*)(Ksw + tbase + r*64 + (size_t)((c ^ (r & 7)) * 8)) = kv;
  }
#pragma unroll
  for (int t = 0; t < 2; t++){
    const int task = t*256 + tid;
    const int r = task >> 3, c = task & 7;
    *(uint4*)(Ls + r*72 + c*8) =
        *(const uint4*)(QKV + (rb + st*64 + r)*QKV_DIM + 2560 + hk*HEAD_DIM + c*8);
  }
  __syncthreads();
#pragma unroll
  for (int t = 0; t < 2; t++){
    const int task = t*256 + tid;
    const int d = task >> 3, sc = task & 7;
    union { u16 h[8]; uint4 v; } tmp;
#pragma unroll
    for (int e = 0; e < 8; e++){
      const int key = ((2*(sc>>2) + (e>>2))<<4) + ((sc&3)<<2) + (e&3);
      tmp.h[e] = Ls[key*72 + d];
    }
    *(uint4*)(Vsw + tbase + d*64 + (size_t)((sc ^ (d & 7)) * 8)) = tmp.v;
  }
}

// attn: 512 threads / 8 waves, QBLK=128, KVBLK=128, LPT 1-D dispatch
// (longest blocks first). Per-thread dataflow = R23 verbatim.
__global__ __launch_bounds__(512)
void attn(const u16* __restrict__ Q, const u16* __restrict__ Ksw,
          const u16* __restrict__ Vsw, u16* __restrict__ O, int qs){
  __shared__ __attribute__((aligned(16))) u16 Ks[2][2*4096];
  __shared__ __attribute__((aligned(16))) u16 Vt[2][2*4096];
  const int tid = threadIdx.x;
  const int wid = tid >> 6, lane = tid & 63, quad = lane >> 4, l16 = lane & 15;
  // LPT decode: longest (tb=15) blocks dispatch first; 64 blocks per tb.
  const int bid = blockIdx.x;
  const int tb = 15 - (bid >> 6);          // q-rows [tb*128, tb*128+128)
  const int h = bid & 31;
  const int b = (bid >> 5) & 1;
  const int hk = h >> 2;
  const size_t rb = (size_t)b * SEQ;
  const size_t hb = ((size_t)(b*8 + hk)) * 32;

  const int jmaxw = 2*tb + (wid >> 2);        // last 64-key tile THIS wave needs
  const int qrow  = (wid & 3)*16 + l16;       // row within this wave's diag tile
  const int sw = l16 & 7;

  bf16x8 qf[2];
  {
    const u16* qp = Q + (rb + tb*128 + wid*16 + l16)*qs + h*HEAD_DIM;
    qf[0] = *(const bf16x8*)(qp + quad*8);
    qf[1] = *(const bf16x8*)(qp + 32 + quad*8);
  }
  const f32x4 zero = {0.f, 0.f, 0.f, 0.f};
  f32x4 oacc[4];
#pragma unroll
  for (int i = 0; i < 4; i++) oacc[i] = zero;
  float m_i = -INFINITY;
  float l_i = 0.f;

  // stage tile PAIR p (tiles 2p, 2p+1) into buffer buf_: 4 gload16/thread
#define STAGE_P(p_, buf_)                                                     \
  {                                                                           \
    const size_t t0 = (hb + 2*(size_t)(p_)) * 4096;                           \
    gload16(Ksw + t0        + wid*512 + lane*8, &Ks[buf_][wid*512]);          \
    gload16(Ksw + t0 + 4096 + wid*512 + lane*8, &Ks[buf_][4096 + wid*512]);   \
    gload16(Vsw + t0        + wid*512 + lane*8, &Vt[buf_][wid*512]);          \
    gload16(Vsw + t0 + 4096 + wid*512 + lane*8, &Vt[buf_][4096 + wid*512]);   \
  }

  const int NP = tb + 1;   // pairs; tile count per block = 2tb+2 (even)
  STAGE_P(0, 0);
  int cur = 0;

  for (int p = 0; p < NP; ++p){
    __syncthreads();   // pair p staged & visible; prior reads of cur^1 done
    if (p + 1 < NP) STAGE_P(p + 1, cur^1);

#pragma unroll
    for (int s = 0; s < 2; ++s){
      const int j = 2*p + s;
      if (j <= jmaxw){   // wave-uniform causal skip
        const u16* Ksb = &Ks[cur][s*4096];
        const u16* Vtb = &Vt[cur][s*4096];

        f32x4 st[4];
#pragma unroll
        for (int ni = 0; ni < 4; ni++){
          f32x4 sacc = zero;
#pragma unroll
          for (int ss = 0; ss < 2; ss++){
            bf16x8 kf = *(const bf16x8*)(Ksb + ((ni*16 + l16) << 6) +
                                         (((ss*4 + quad) ^ sw) << 3));
            sacc = __builtin_amdgcn_mfma_f32_16x16x32_bf16(kf, qf[ss], sacc, 0, 0, 0);
          }
          st[ni] = sacc;
        }
        if (j == jmaxw){
#pragma unroll
          for (int ni = 0; ni < 4; ni++)
#pragma unroll
            for (int r = 0; r < 4; r++)
              if (ni*16 + quad*4 + r > qrow) st[ni][r] = -INFINITY;
        }

        float mx = fmaxf(fmaxf(fmaxf(st[0][0], st[0][1]), fmaxf(st[0][2], st[0][3])),
                         fmaxf(fmaxf(st[1][0], st[1][1]), fmaxf(st[1][2], st[1][3])));
        mx = fmaxf(mx, fmaxf(fmaxf(fmaxf(st[2][0], st[2][1]), fmaxf(st[2][2], st[2][3])),
                             fmaxf(fmaxf(st[3][0], st[3][1]), fmaxf(st[3][2], st[3][3]))));
        mx = fmaxf(mx, __shfl_xor(mx, 16));
        mx = fmaxf(mx, __shfl_xor(mx, 32));

        if (__all(mx <= m_i + 10.f)){
          float ps = 0.f;
#pragma unroll
          for (int ni = 0; ni < 4; ni++)
#pragma unroll
            for (int r = 0; r < 4; r++){
              const float pv = exp2_fast(st[ni][r] - m_i);
              st[ni][r] = pv;
              ps += pv;
            }
          ps += __shfl_xor(ps, 16);
          ps += __shfl_xor(ps, 32);
          l_i += ps;
        } else {
          const float mn = fmaxf(m_i, mx);
          const float alpha = exp2_fast(m_i - mn);
          float ps = 0.f;
#pragma unroll
          for (int ni = 0; ni < 4; ni++)
#pragma unroll
            for (int r = 0; r < 4; r++){
              const float pv = exp2_fast(st[ni][r] - mn);
              st[ni][r] = pv;
              ps += pv;
            }
          ps += __shfl_xor(ps, 16);
          ps += __shfl_xor(ps, 32);
          l_i = l_i*alpha + ps;
          m_i = mn;
          float ar[4];
#pragma unroll
          for (int r = 0; r < 4; r++) ar[r] = __shfl(alpha, quad*4 + r);
#pragma unroll
          for (int ci = 0; ci < 4; ci++)
#pragma unroll
            for (int r = 0; r < 4; r++) oacc[ci][r] *= ar[r];
        }

        bf16x8 pfr[2];
#pragma unroll
        for (int ss = 0; ss < 2; ss++){
          union { uint32_t w[4]; bf16x8 v; } pk;
          pk.w[0] = cvt_pk_bf16(st[2*ss][0],   st[2*ss][1]);
          pk.w[1] = cvt_pk_bf16(st[2*ss][2],   st[2*ss][3]);
          pk.w[2] = cvt_pk_bf16(st[2*ss+1][0], st[2*ss+1][1]);
          pk.w[3] = cvt_pk_bf16(st[2*ss+1][2], st[2*ss+1][3]);
          pfr[ss] = pk.v;
        }

#pragma unroll
        for (int ss = 0; ss < 2; ss++)
#pragma unroll
          for (int ci = 0; ci < 4; ci++){
            bf16x8 vf = *(const bf16x8*)(Vtb + ((ci*16 + l16) << 6) +
                                         (((ss*4 + quad) ^ sw) << 3));
            oacc[ci] = __builtin_amdgcn_mfma_f32_16x16x32_bf16(pfr[ss], vf, oacc[ci], 0, 0, 0);
          }
      }
    }
    cur ^= 1;
  }
#undef STAGE_P

  float lf[4];
#pragma unroll
  for (int r = 0; r < 4; r++) lf[r] = __shfl(l_i, quad*4 + r);
#pragma unroll
  for (int ci = 0; ci < 4; ci++)
#pragma unroll
    for (int r = 0; r < 4; r++){
      const size_t row = rb + tb*128 + wid*16 + quad*4 + r;
      O[row*D_MODEL + h*HEAD_DIM + ci*16 + l16] = f2bf(oacc[ci][r] / lf[r]);
    }
}

extern "C" void kernel_launch(void* const* d_in, const int* in_sizes, int n_in,
                              void* d_out, int out_size, void* d_ws, size_t ws_size,
                              hipStream_t stream){
  const float* x  = (const float*)d_in[0];
  const float* Wq = (const float*)d_in[1];
  const float* Wk = (const float*)d_in[2];
  const float* Wv = (const float*)d_in[3];
  const float* Wo = (const float*)d_in[4];
  float* out = (float*)d_out;

  u16* xb   = (u16*)d_ws;                    // x / later attn-out  [4096,2048]
  u16* Wb   = xb + (size_t)MTOT*D_MODEL;     // fused weights [3072,2048]
  u16* Wob  = Wb + (size_t)QKV_DIM*D_MODEL;  // Wo bf16 [2048,2048] (if ws fits)
  u16* QKVb = (u16*)d_out;                   // QKV scratch [4096,3072] bf16
  u16* Kswz = Wb;                            // swizzled K tiles (Wq region, dead after gemm1)
  u16* Vswz = Wb + (size_t)2*1024*1024;      // swizzled V tiles

  const int nwq = D_MODEL*D_MODEL;
  const float QSCL = 0.125f * 1.44269504f;   // softmax scale * log2(e)

  const size_t ws_need = ((size_t)MTOT*D_MODEL + (size_t)QKV_DIM*D_MODEL +
                          (size_t)D_MODEL*D_MODEL) * sizeof(u16);
  const bool wob_fits = (ws_size >= ws_need);

  if (wob_fits){
    cvt_all<<<9216, 256, 0, stream>>>(x, Wq, Wk, Wv, Wo, xb, Wb, Wob, QSCL);
  } else {
    cvt_all<<<7168, 256, 0, stream>>>(x, Wq, Wk, Wv, Wo, xb, Wb, Wob, QSCL);
  }
  gemm_bt<false><<<(QKV_DIM/128)*(MTOT/128), 256, 0, stream>>>(
      xb, Wb, QKVb, MTOT, QKV_DIM, D_MODEL, QKV_DIM/128);
  kvtrans<<<dim3(SEQ/64, 8, 2), 256, 0, stream>>>(QKVb, Kswz, Vswz);
  attn<<<1024, 512, 0, stream>>>(QKVb, Kswz, Vswz, xb, QKV_DIM);
  const u16* Bw2;
  if (wob_fits){
    Bw2 = Wob;
  } else {
    cvt_bf16<<<nwq/2048, 256, 0, stream>>>(Wo, Wb, nwq, 1.0f);
    Bw2 = Wb;
  }
  gemm_bt<true><<<(D_MODEL/128)*(MTOT/128), 256, 0, stream>>>(
      xb, Bw2, (void*)out, MTOT, D_MODEL, D_MODEL, D_MODEL/128);
}